// Round 7
// baseline (2735.788 us; speedup 1.0000x reference)
//
#include <hip/hip_runtime.h>
#include <math.h>

// Glacier SIA stepper. 128 persistent blocks x 512 threads, thread = column.
// ALL stencil state in registers (rows of own column); j+-1 neighbors via
// wave shuffles; the 8 wave-seam columns go through a ~1.3KB LDS seam table
// (written by lanes 0/63 only, merged into the existing 3 barriers).
// Cross-block sync: depth-2 epoch-tagged ring, direct 128-wide gather
// (threads 0..127), per-wave neighbor flag polls. Relaxed agent-scope
// atomics for all cross-block data; no threadfences.
//
// Register-slot maps (per column j):
//   zs[s]  = Zs row a-2+s   (s=0..7; 0 and 7 are halo rows)
//   Dv[ld] = D  row a-2+ld  (ld=0..6; 0 and 6 are halo rows)
//   h/hn/smbr/dH[ln] = row a-1+ln (ln=0..5)
//   H row i needs D rows i-1,i  ->  ld = ln, ln+1   (edge ln=5: ld 5,6!)
//
// ws layout (bytes):
//   0     : ull ring[2][128] lines (stride 128 B) {epoch<<32 | blockMax bits}
//   32768 : float Ha[MM], Hb[MM], Da[MM], Db[MM] (published-row ping-pong)
// First 32768 B zeroed by captured hipMemsetAsync each call.

#define NN 512
#define MM (NN * NN)
#define NSTEPS 400
#define NW 128
#define HR 4
#define TPB 512

typedef unsigned long long ull;

__device__ __forceinline__ ull ald(const ull* p) {
  return __hip_atomic_load(p, __ATOMIC_RELAXED, __HIP_MEMORY_SCOPE_AGENT);
}
__device__ __forceinline__ void asto(ull* p, ull v) {
  __hip_atomic_store(p, v, __ATOMIC_RELAXED, __HIP_MEMORY_SCOPE_AGENT);
}
__device__ __forceinline__ float cload(const float* p) {
  return __hip_atomic_load(p, __ATOMIC_RELAXED, __HIP_MEMORY_SCOPE_AGENT);
}
__device__ __forceinline__ void cstore(float* p, float v) {
  __hip_atomic_store(p, v, __ATOMIC_RELAXED, __HIP_MEMORY_SCOPE_AGENT);
}

__global__ __launch_bounds__(TPB)
void glacier_kernel(const float* __restrict__ Zt,
                    const float* __restrict__ precip,
                    const float* __restrict__ Tm,
                    const float* __restrict__ Ts,
                    float* __restrict__ out,        // [3*MM]: H1, H2, H
                    ull* __restrict__ ring,         // [2][128] lines
                    float* __restrict__ Ha, float* __restrict__ Hb,
                    float* __restrict__ Da, float* __restrict__ Db) {
  // seam tables: [wave][slot]; e* written by lane0 (east-source for wave-1's
  // lane63), w* written by lane63 (west-source for wave+1's lane0)
  __shared__ float eZS[8][8], wZS[8][8], wD[8][8], eHN[8][8], eZN[8][8];
  __shared__ float wmax[8];
  __shared__ float gmax2[2];

  const int w = blockIdx.x;
  const int j = threadIdx.x;          // column
  const int lane = j & 63;
  const int wv = j >> 6;
  const int wvm = (wv == 0) ? 0 : wv - 1;
  const int wvp = (wv == 7) ? 7 : wv + 1;
  const int a = w * HR;               // first owned row
  const float TmTs = Tm[0] + Ts[0];
  const double RG = 910.0 * 9.81;
  const float CDIF = (float)(1e-16 * RG * RG * RG);

  float zt[HR + 4], zs[HR + 4];       // rows a-2 .. a+5
  float h[HR + 2], smbr[HR + 2];      // rows a-1 .. a+4
  float Dv[HR + 3];                   // D rows a-2 .. a+4

  // ---- prologue (no cross-block deps)
#pragma unroll
  for (int s = 0; s < HR + 4; ++s) {
    int r = a - 2 + s;
    zt[s] = (r >= 0 && r < NN) ? Zt[r * NN + j] : 0.f;
    zs[s] = zt[s];                    // H = 0
  }
#pragma unroll
  for (int ln = 0; ln < HR + 2; ++ln) {
    int r = a - 1 + ln;
    h[ln] = 0.f;
    float sm = 0.f;
    if (r >= 0 && r < NN) {
      float T = TmTs - 0.006f * zt[ln + 1];
      sm = precip[r * NN + j] - 0.5f * fmaxf(T, 0.f);
    }
    smbr[ln] = sm;
  }
#pragma unroll
  for (int ld = 0; ld < HR + 3; ++ld) Dv[ld] = 1e-10f;      // D(H=0) exactly
#pragma unroll
  for (int rr = 0; rr < HR; ++rr) {
    int id = (a + rr) * NN + j;
    out[id] = 0.f;
    out[MM + id] = 0.f;
  }
  if (lane == 0) {
#pragma unroll
    for (int s = 1; s <= HR + 2; ++s) eZS[wv][s] = zs[s];
  }
  if (lane == 63) {
#pragma unroll
    for (int s = 1; s <= HR + 2; ++s) wZS[wv][s] = zs[s];
#pragma unroll
    for (int ld = 1; ld <= HR + 1; ++ld) wD[wv][ld] = Dv[ld];
  }
  __syncthreads();

  float time = 0.f, t_last = 0.f;
  int idx = 0;
  bool s1 = false, s2 = false;

  for (int k = 0; k < NSTEPS; ++k) {
    if (time >= 200.0f) break;                  // uniform (dt identical)

    const float* Hrd = (k & 1) ? Hb : Ha;
    float* Hwr = (k & 1) ? Ha : Hb;
    const float* Drd = (k & 1) ? Db : Da;
    float* Dwr = (k & 1) ? Da : Db;
    ull* ringp = ring + (size_t)(k & 1) * NW * 16;

    // ---- top samples (issue early)
    bool pre = (time - t_last) >= 4.0f;         // exact-safe precip gate
    int idxn = min(idx + 1, 63);
    float pf[HR + 2];
    if (pre) {
      const float* prowN = precip + (size_t)idxn * MM;
#pragma unroll
      for (int ln = 0; ln < HR + 2; ++ln) {
        int i = a - 1 + ln;
        pf[ln] = (i >= 0 && i < NN) ? prowN[i * NN + j] : 0.f;
      }
    } else {
#pragma unroll
      for (int ln = 0; ln < HR + 2; ++ln) pf[ln] = 0.f;
    }
    const ull* np = nullptr; ull ns = 0;
    const ull* gp = nullptr; ull gv = 0;
    if (k > 0) {
      if (lane < 2) {                           // per-wave neighbor sample
        int nb = (lane == 0) ? w - 1 : w + 1;
        if (nb >= 0 && nb < NW) { np = ringp + nb * 16; ns = ald(np); }
      }
      if (j < NW) { gp = ringp + j * 16; gv = ald(gp); }   // gather sample
    }
    asm volatile("" ::: "memory");

    // ---- W/E neighbor values via shfl + seams (halo-independent rows)
    float zsW[HR + 4], zsE[HR + 4], dWl[HR + 3];
#pragma unroll
    for (int s = 1; s <= HR + 2; ++s) {
      float up = __shfl_up(zs[s], 1);
      float dn = __shfl_down(zs[s], 1);
      zsW[s] = (lane == 0) ? wZS[wvm][s] : up;
      zsE[s] = (lane == 63) ? eZS[wvp][s] : dn;
    }
#pragma unroll
    for (int ld = 1; ld <= HR + 1; ++ld) {
      float up = __shfl_up(Dv[ld], 1);
      dWl[ld] = (lane == 0) ? wD[wvm][ld] : up;
    }

    // ---- mid dHdt rows a..a+3 (halo-free; hides flag-sample RT)
    float dH[HR + 2];
#pragma unroll
    for (int ln = 1; ln <= HR; ++ln) {
      int i = a - 1 + ln;
      float v = 0.f;
      if (i > 0 && i < NN - 1 && j > 0 && j < NN - 1) {
        float zc = zs[ln + 1], zw = zsW[ln + 1], ze = zsE[ln + 1];
        float zn = zs[ln], zso = zs[ln + 2];
        float d00 = dWl[ln], d01 = Dv[ln], d10 = dWl[ln + 1], d11 = Dv[ln + 1];
        float qx0 = -(0.5f * (d00 + d10)) * (zc - zw) / 200.f;
        float qx1 = -(0.5f * (d01 + d11)) * (ze - zc) / 200.f;
        float qy0 = -(0.5f * (d00 + d01)) * (zc - zn) / 200.f;
        float qy1 = -(0.5f * (d10 + d11)) * (zso - zc) / 200.f;
        v = -((qx1 - qx0) / 200.f + (qy1 - qy0) / 200.f);
      }
      dH[ln] = v;
    }

    // ---- neighbor flag spin -> halo cloads -> gather spin (RTs overlap)
    bool top = (a - 2 >= 0), bot5 = (a + 5 < NN), bot4 = (a + 4 < NN - 1);
    if (k > 0) {
      if (np) {
        while ((unsigned)(ns >> 32) < (unsigned)k) {
          __builtin_amdgcn_s_sleep(1);
          ns = ald(np);
        }
      }
      asm volatile("" ::: "memory");            // cloads stay after the spin
      float htop = 0.f, dtop = 0.f, hbot = 0.f, dbot = 0.f;
      if (top)  { htop = cload(Hrd + (a - 2) * NN + j);
                  dtop = cload(Drd + (a - 2) * NN + j); }
      if (bot5)   hbot = cload(Hrd + (a + 5) * NN + j);
      if (bot4)   dbot = cload(Drd + (a + 4) * NN + j);
      if (j < NW) {                             // direct gather (waves 0,1)
        while ((unsigned)(gv >> 32) < (unsigned)k) {
          __builtin_amdgcn_s_sleep(1);
          gv = ald(gp);
        }
        float lm = __uint_as_float((unsigned)gv);
        for (int off = 32; off; off >>= 1) lm = fmaxf(lm, __shfl_xor(lm, off));
        if (lane == 0) gmax2[j >> 6] = lm;
      }
      if (top)  { zs[0] = zt[0] + htop; Dv[0] = dtop; }
      if (bot5)   zs[HR + 3] = zt[HR + 3] + hbot;
      if (bot4)   Dv[HR + 2] = dbot;
    }
    if (lane == 63) { wD[wv][0] = Dv[0]; wD[wv][6] = Dv[HR + 2]; }
    __syncthreads();                            // sync1: halo D seams + gmax2

    // ---- edge dHdt rows a-1 (ln=0: D ld 0,1) and a+4 (ln=5: D ld 5,6)
    {
      float up0 = __shfl_up(Dv[0], 1);
      float up6 = __shfl_up(Dv[HR + 2], 1);
      float dW0 = (lane == 0) ? wD[wvm][0] : up0;
      float dW6 = (lane == 0) ? wD[wvm][6] : up6;
#pragma unroll
      for (int e = 0; e < 2; ++e) {
        int ln = (e == 0) ? 0 : HR + 1;
        int i = a - 1 + ln;
        float v = 0.f;
        if (i > 0 && i < NN - 1 && j > 0 && j < NN - 1) {
          float zc = zs[ln + 1], zw = zsW[ln + 1], ze = zsE[ln + 1];
          float zn = zs[ln], zso = zs[ln + 2];
          float d00 = (e == 0) ? dW0    : dWl[HR + 1];   // D row i-1, west
          float d01 = (e == 0) ? Dv[0]  : Dv[HR + 1];    // D row i-1
          float d10 = (e == 0) ? dWl[1] : dW6;           // D row i,   west
          float d11 = (e == 0) ? Dv[1]  : Dv[HR + 2];    // D row i
          float qx0 = -(0.5f * (d00 + d10)) * (zc - zw) / 200.f;
          float qx1 = -(0.5f * (d01 + d11)) * (ze - zc) / 200.f;
          float qy0 = -(0.5f * (d00 + d01)) * (zc - zn) / 200.f;
          float qy1 = -(0.5f * (d10 + d11)) * (zso - zc) / 200.f;
          v = -((qx1 - qx0) / 200.f + (qy1 - qy0) / 200.f);
        }
        dH[ln] = v;
      }
    }

    float maxD = (k == 0) ? 1e-10f : fmaxf(gmax2[0], gmax2[1]);
    float dt = fminf(40000.0f / (2.7f * maxD), 1.0f);
    float tnew = time + dt;
    bool cap1 = (!s1) && (tnew >= 120.0f);
    bool cap2 = (!s2) && (tnew >= 160.0f);
    bool do_upd = (tnew - t_last) >= 5.0f;

    // ---- part B: H update, publishes, captures, smb refresh (registers)
    float hn[HR + 2], zsn[HR + 2];
#pragma unroll
    for (int ln = 0; ln < HR + 2; ++ln) {
      int i = a - 1 + ln;
      float hnew = 0.f;
      if (i >= 0 && i < NN) {
        if (i > 0 && i < NN - 1 && j > 0 && j < NN - 1)
          hnew = fmaxf(h[ln] + dt * (dH[ln] + smbr[ln]), 0.f);
        float z = zt[ln + 1] + hnew;
        zsn[ln] = z;
        if (i == a + 1 || i == a + 2) cstore(Hwr + i * NN + j, hnew);
        if (i >= a && i < a + HR) {
          int id = i * NN + j;
          if (cap1) out[id] = hnew;
          if (cap2) out[MM + id] = hnew;
        }
        if (do_upd)
          smbr[ln] = pf[ln] - 0.5f * fmaxf(TmTs - 0.006f * z, 0.f);
      } else {
        zsn[ln] = zt[ln + 1];                   // hnew = 0
      }
      hn[ln] = hnew;
    }
    if (lane == 0) {
#pragma unroll
      for (int ln = 0; ln < HR + 2; ++ln) { eHN[wv][ln] = hn[ln]; eZN[wv][ln] = zsn[ln]; }
    }
    __syncthreads();                            // sync2: hn/zsn east seams

    // ---- phase 2: new D rows a-1..a+3 (registers+shfl) + block max
    float hnE[HR + 2], znE[HR + 2];
#pragma unroll
    for (int ln = 0; ln < HR + 2; ++ln) {
      float hdn = __shfl_down(hn[ln], 1);
      float zdn = __shfl_down(zsn[ln], 1);
      hnE[ln] = (lane == 63) ? eHN[wvp][ln] : hdn;
      znE[ln] = (lane == 63) ? eZN[wvp][ln] : zdn;
    }
    float lmax = 0.f;
#pragma unroll
    for (int ln = 0; ln < HR + 1; ++ln) {
      int r = a - 1 + ln;
      if (r >= 0 && r < NN - 1 && j < NN - 1) {
        float h00 = hn[ln], h01 = hnE[ln], h10 = hn[ln + 1], h11 = hnE[ln + 1];
        float z00 = zsn[ln], z01 = znE[ln], z10 = zsn[ln + 1], z11 = znE[ln + 1];
        float havg = 0.25f * (((h00 + h11) + h01) + h10);
        float sx = 0.5f * ((z01 - z00) / 200.f + (z11 - z10) / 200.f);
        float sy = 0.5f * ((z10 - z00) / 200.f + (z11 - z01) / 200.f);
        float sn = sqrtf((sx * sx + sy * sy) + 1e-10f);
        float h2 = havg * havg;
        float h4 = h2 * h2;
        float h5 = h4 * havg;
        float d = CDIF * h5 * (sn * sn) + 1e-10f;
        Dv[ln + 1] = d;
        if (r == a || r == a + 2) cstore(Dwr + r * NN + j, d);
        lmax = fmaxf(lmax, d);
      }
    }
    for (int off = 32; off; off >>= 1) lmax = fmaxf(lmax, __shfl_xor(lmax, off));
    if (lane == 0) wmax[wv] = lmax;

    // ---- state roll + next-step seams (merged into sync3)
#pragma unroll
    for (int ln = 0; ln < HR + 2; ++ln) h[ln] = hn[ln];
#pragma unroll
    for (int s = 1; s <= HR + 2; ++s) zs[s] = zsn[s - 1];
    if (lane == 0) {
#pragma unroll
      for (int s = 1; s <= HR + 2; ++s) eZS[wv][s] = zs[s];
    }
    if (lane == 63) {
#pragma unroll
      for (int s = 1; s <= HR + 2; ++s) wZS[wv][s] = zs[s];
#pragma unroll
      for (int ld = 1; ld <= HR + 1; ++ld) wD[wv][ld] = Dv[ld];
    }
    __syncthreads();    // sync3: wmax + seams; drains publishes (vmcnt)
    if (j == 0) {
      float bm = wmax[0];
#pragma unroll
      for (int q = 1; q < 8; ++q) bm = fmaxf(bm, wmax[q]);
      asto(ring + (size_t)((k + 1) & 1) * NW * 16 + w * 16,
           ((ull)(unsigned)(k + 1) << 32) | __float_as_uint(bm));
    }

    // ---- bookkeeping
    time = tnew;
    s1 = s1 || cap1;
    s2 = s2 || cap2;
    if (do_upd) { idx = idxn; t_last = tnew; }
  }

  // ---- final H (owned rows a+rr -> h slot rr+1)
#pragma unroll
  for (int rr = 0; rr < HR; ++rr)
    out[2 * MM + (a + rr) * NN + j] = h[rr + 1];
}

extern "C" void kernel_launch(void* const* d_in, const int* in_sizes, int n_in,
                              void* d_out, int out_size, void* d_ws, size_t ws_size,
                              hipStream_t stream) {
  const float* Zt = (const float*)d_in[0];
  const float* precip = (const float*)d_in[1];
  const float* Tm = (const float*)d_in[2];
  const float* Ts = (const float*)d_in[3];
  float* out = (float*)d_out;

  ull* ring = (ull*)d_ws;                            // 2*128 lines @ 128 B
  float* Ha = (float*)((char*)d_ws + 32768);
  float* Hb = Ha + MM;
  float* Da = Hb + MM;
  float* Db = Da + MM;

  hipMemsetAsync(d_ws, 0, 32768, stream);            // ring tags -> 0
  glacier_kernel<<<NW, TPB, 0, stream>>>(Zt, precip, Tm, Ts, out,
                                         ring, Ha, Hb, Da, Db);
}